// Round 1
// baseline (537.204 us; speedup 1.0000x reference)
//
#include <hip/hip_runtime.h>
#include <stdint.h>

#define BB 8
#define NN 100000
#define CC 18
#define DD 128
#define NCROSS 1024
#define TOPK 256
#define NBINS 8192
#define CCAP 4096

// d_out float offsets (outputs concatenated flat in return order)
#define OFF_PTS 0
#define OFF_FEAT 6144
#define OFF_SI 268288
#define OFF_CROSS 270336

// sigmoid with correctly-rounded f32 exp (exp computed in double, rounded to
// f32, then f32 arithmetic) — mimics a canonical numpy float32 pipeline
__device__ __forceinline__ float sigf(float x) {
  float e = (float)exp(-(double)x);
  return 1.0f / (1.0f + e);
}

__global__ void k_init(uint32_t* __restrict__ p, int n) {
  int i = blockIdx.x * 256 + threadIdx.x;
  if (i < n) p[i] = 0u;
}

__global__ void k_score(const float* __restrict__ cen, const float* __restrict__ cls,
                        uint32_t* __restrict__ keys, uint32_t* __restrict__ hist) {
  int i = blockIdx.x * 256 + threadIdx.x;
  if (i >= BB * NN) return;
  int b = i / NN;
  const float2* p2 = (const float2*)(cls + (size_t)i * CC);
  float m = -INFINITY;
#pragma unroll
  for (int c = 0; c < CC / 2; ++c) {
    float2 v = p2[c];
    m = fmaxf(m, fmaxf(v.x, v.y));
  }
  // max_c fl(sig_cen*sig_cls_c) == fl(sig_cen * sig(max_c cls_c)) exactly
  // (monotone rounding, monotone sigmoid)
  float s = sigf(m) * sigf(cen[i]);
  uint32_t k = __float_as_uint(s);  // s >= 0 -> raw bits are order-preserving
  keys[i] = k;
  atomicAdd(&hist[b * NBINS + (k >> 19)], 1u);
}

__global__ void k_select(const uint32_t* __restrict__ hist, uint32_t* __restrict__ cutoff) {
  int b = blockIdx.x;
  int t = threadIdx.x;
  __shared__ uint32_t h[NBINS];     // 32 KB
  __shared__ uint32_t csum[256];
  for (int j = t; j < NBINS; j += 256) h[j] = hist[b * NBINS + j];
  __syncthreads();
  // chunk sums (rotated access -> 2 lanes/bank, conflict-free)
  uint32_t s = 0;
  int base = t * 32;
#pragma unroll
  for (int j = 0; j < 32; ++j) s += h[base + ((j + t) & 31)];
  csum[t] = s;
  __syncthreads();
  // suffix scan over 256 chunks
  for (int off = 1; off < 256; off <<= 1) {
    uint32_t v = csum[t];
    uint32_t a = (t + off < 256) ? csum[t + off] : 0u;
    __syncthreads();
    csum[t] = v + a;
    __syncthreads();
  }
  uint32_t St = csum[t];
  uint32_t St1 = (t < 255) ? csum[t + 1] : 0u;
  if (St >= NCROSS && St1 < NCROSS) {
    // crossing chunk: walk its bins from the top
    uint32_t acc = St1;
    int cb = base;
    for (int bin = base + 31; bin >= base; --bin) {
      acc += h[bin];
      if (acc >= NCROSS) { cb = bin; break; }
    }
    cutoff[b] = (uint32_t)cb;
  }
}

__global__ void k_compact(const uint32_t* __restrict__ keys, const uint32_t* __restrict__ cutoff,
                          uint32_t* __restrict__ cand_cnt, uint32_t* __restrict__ cand_key,
                          uint32_t* __restrict__ cand_idx) {
  int i = blockIdx.x * 256 + threadIdx.x;
  if (i >= BB * NN) return;
  int b = i / NN;
  int n = i - b * NN;
  uint32_t k = keys[i];
  if ((k >> 19) >= cutoff[b]) {
    uint32_t pos = atomicAdd(&cand_cnt[b], 1u);
    if (pos < CCAP) {
      cand_key[b * CCAP + pos] = k;
      cand_idx[b * CCAP + pos] = (uint32_t)n;
    }
  }
}

__global__ void k_rank(const uint32_t* __restrict__ cand_cnt, const uint32_t* __restrict__ cand_key,
                       const uint32_t* __restrict__ cand_idx, uint32_t* __restrict__ ordered) {
  int b = blockIdx.y;
  int g = blockIdx.x;
  uint32_t cnt = cand_cnt[b];
  if (cnt > CCAP) cnt = CCAP;
  int base = g * 256;
  if (base >= (int)cnt) return;  // uniform per block
  __shared__ uint64_t comp[CCAP];  // 32 KB
  for (int j = threadIdx.x; j < (int)cnt; j += 256) {
    comp[j] = ((uint64_t)cand_key[b * CCAP + j] << 32) | (uint32_t)(~cand_idx[b * CCAP + j]);
  }
  __syncthreads();
  int j0 = base + threadIdx.x;
  if (j0 < (int)cnt) {
    uint64_t mine = comp[j0];
    uint32_t r = 0;
    for (uint32_t j = 0; j < cnt; ++j) r += (comp[j] > mine) ? 1u : 0u;  // broadcast reads
    if (r < NCROSS) ordered[b * NCROSS + r] = ~(uint32_t)mine;  // recover idx
  }
}

__global__ void k_sort256(const uint32_t* __restrict__ ordered, uint32_t* __restrict__ sel,
                          float* __restrict__ out_si) {
  int b = blockIdx.x;
  int t = threadIdx.x;
  __shared__ uint32_t idxs[TOPK];
  uint32_t v = ordered[b * NCROSS + t];
  idxs[t] = v;
  __syncthreads();
  int r = 0;
  for (int j = 0; j < TOPK; ++j) r += (idxs[j] < v) ? 1 : 0;
  sel[b * TOPK + r] = v;
  out_si[b * TOPK + r] = (float)v;  // flat out buffer is read as f32
}

__global__ void k_gather(const float* __restrict__ features, const float* __restrict__ points,
                         const uint32_t* __restrict__ ordered, const uint32_t* __restrict__ sel,
                         float* __restrict__ out) {
  int g = blockIdx.x;
  int t = threadIdx.x;
  if (g < 1024) {  // cross_features: 8*1024 rows * 32 float4
    int flat = g * 256 + t;
    int row = flat >> 5;
    int c4 = flat & 31;
    int b = row >> 10, j = row & 1023;
    uint32_t idx = ordered[b * NCROSS + j];
    const float4* src = (const float4*)(features + ((size_t)b * NN + idx) * DD);
    ((float4*)(out + OFF_CROSS))[flat] = src[c4];
  } else if (g < 1280) {  // feat_sel: 8*256 rows * 32 float4
    int flat = (g - 1024) * 256 + t;
    int row = flat >> 5;
    int c4 = flat & 31;
    int b = row >> 8, j = row & 255;
    uint32_t idx = sel[b * TOPK + j];
    const float4* src = (const float4*)(features + ((size_t)b * NN + idx) * DD);
    ((float4*)(out + OFF_FEAT))[flat] = src[c4];
  } else {  // pts_sel: 8 blocks, 256 rows each, 3 floats
    int b = g - 1280;
    uint32_t idx = sel[b * TOPK + t];
    const float* src = points + ((size_t)b * NN + idx) * 3;
    float* dst = out + OFF_PTS + ((size_t)b * TOPK + t) * 3;
    dst[0] = src[0];
    dst[1] = src[1];
    dst[2] = src[2];
  }
}

extern "C" void kernel_launch(void* const* d_in, const int* in_sizes, int n_in,
                              void* d_out, int out_size, void* d_ws, size_t ws_size,
                              hipStream_t stream) {
  const float* cen  = (const float*)d_in[0];
  const float* cls  = (const float*)d_in[1];
  const float* pts  = (const float*)d_in[2];
  const float* feat = (const float*)d_in[3];
  float* out = (float*)d_out;

  uint32_t* ws = (uint32_t*)d_ws;
  uint32_t* hist     = ws;                      // BB*NBINS
  uint32_t* cand_cnt = hist + BB * NBINS;       // BB
  uint32_t* cutoff   = cand_cnt + BB;           // BB
  uint32_t* cand_key = cutoff + BB;             // BB*CCAP
  uint32_t* cand_idx = cand_key + BB * CCAP;    // BB*CCAP
  uint32_t* ordered  = cand_idx + BB * CCAP;    // BB*NCROSS
  uint32_t* sel      = ordered + BB * NCROSS;   // BB*TOPK
  uint32_t* keys     = sel + BB * TOPK;         // BB*NN

  int nz = BB * NBINS + BB;  // hist + cand_cnt (adjacent)
  k_init<<<(nz + 255) / 256, 256, 0, stream>>>(hist, nz);
  k_score<<<(BB * NN + 255) / 256, 256, 0, stream>>>(cen, cls, keys, hist);
  k_select<<<BB, 256, 0, stream>>>(hist, cutoff);
  k_compact<<<(BB * NN + 255) / 256, 256, 0, stream>>>(keys, cutoff, cand_cnt, cand_key, cand_idx);
  k_rank<<<dim3(CCAP / 256, BB), 256, 0, stream>>>(cand_cnt, cand_key, cand_idx, ordered);
  k_sort256<<<BB, 256, 0, stream>>>(ordered, sel, out + OFF_SI);
  k_gather<<<1288, 256, 0, stream>>>(feat, pts, ordered, sel, out);
}

// Round 2
// 158.385 us; speedup vs baseline: 3.3918x; 3.3918x over previous
//
#include <hip/hip_runtime.h>
#include <stdint.h>

#define BB 8
#define NN 100000
#define CC 18
#define DD 128
#define NCROSS 1024
#define TOPK 256
#define NBINS 8192
#define CCAP 4096
#define SEG 3125          // NN / 32

// d_out float offsets (outputs concatenated flat in return order)
#define OFF_PTS 0
#define OFF_FEAT 6144
#define OFF_SI 268288
#define OFF_CROSS 270336

// sigmoid with correctly-rounded f32 exp (exp computed in double, rounded to
// f32, then f32 arithmetic) — mimics a canonical numpy float32 pipeline
__device__ __forceinline__ float sigf(float x) {
  float e = (float)exp(-(double)x);
  return 1.0f / (1.0f + e);
}

__global__ void k_init(uint32_t* __restrict__ p, int n) {
  int i = blockIdx.x * 256 + threadIdx.x;
  if (i < n) p[i] = 0u;
}

// 32 blocks per batch; per-block LDS histogram; flush nonzero bins only.
__global__ void k_score(const float* __restrict__ cen, const float* __restrict__ cls,
                        uint32_t* __restrict__ keys, uint32_t* __restrict__ hist) {
  int b = blockIdx.y;
  int seg = blockIdx.x;
  __shared__ uint32_t h[NBINS];  // 32 KB
  for (int j = threadIdx.x; j < NBINS; j += 256) h[j] = 0u;
  __syncthreads();
  int base = b * NN + seg * SEG;
  for (int it = threadIdx.x; it < SEG; it += 256) {
    int i = base + it;
    const float2* p2 = (const float2*)(cls + (size_t)i * CC);
    float m = -INFINITY;
#pragma unroll
    for (int c = 0; c < CC / 2; ++c) {
      float2 v = p2[c];
      m = fmaxf(m, fmaxf(v.x, v.y));
    }
    // max_c fl(sig_cen*sig_cls_c) == fl(sig_cen * sig(max_c cls_c)) exactly
    // (monotone rounding, monotone sigmoid)
    float s = sigf(m) * sigf(cen[i]);
    uint32_t k = __float_as_uint(s);  // s >= 0 -> raw bits order-preserving
    keys[i] = k;
    atomicAdd(&h[k >> 19], 1u);      // LDS atomic: absorbs hot-bin contention
  }
  __syncthreads();
  for (int j = threadIdx.x; j < NBINS; j += 256) {
    uint32_t v = h[j];
    if (v) atomicAdd(&hist[b * NBINS + j], v);  // <=32 atomics per address
  }
}

__global__ void k_select(const uint32_t* __restrict__ hist, uint32_t* __restrict__ cutoff) {
  int b = blockIdx.x;
  int t = threadIdx.x;
  __shared__ uint32_t h[NBINS];     // 32 KB
  __shared__ uint32_t csum[256];
  for (int j = t; j < NBINS; j += 256) h[j] = hist[b * NBINS + j];
  __syncthreads();
  uint32_t s = 0;
  int base = t * 32;
#pragma unroll
  for (int j = 0; j < 32; ++j) s += h[base + ((j + t) & 31)];
  csum[t] = s;
  __syncthreads();
  for (int off = 1; off < 256; off <<= 1) {
    uint32_t v = csum[t];
    uint32_t a = (t + off < 256) ? csum[t + off] : 0u;
    __syncthreads();
    csum[t] = v + a;
    __syncthreads();
  }
  uint32_t St = csum[t];
  uint32_t St1 = (t < 255) ? csum[t + 1] : 0u;
  if (St >= NCROSS && St1 < NCROSS) {
    uint32_t acc = St1;
    int cb = base;
    for (int bin = base + 31; bin >= base; --bin) {
      acc += h[bin];
      if (acc >= NCROSS) { cb = bin; break; }
    }
    cutoff[b] = (uint32_t)cb;
  }
}

// grid (391, BB): a block never straddles a batch -> wave-aggregated atomics
__global__ void k_compact(const uint32_t* __restrict__ keys, const uint32_t* __restrict__ cutoff,
                          uint32_t* __restrict__ cand_cnt, uint32_t* __restrict__ cand_key,
                          uint32_t* __restrict__ cand_idx) {
  int b = blockIdx.y;
  int n = blockIdx.x * 256 + threadIdx.x;
  bool pass = false;
  uint32_t k = 0;
  if (n < NN) {
    k = keys[b * NN + n];
    pass = (k >> 19) >= cutoff[b];
  }
  int lane = threadIdx.x & 63;
  unsigned long long mask = __ballot(pass);
  if (mask) {
    int leader = __ffsll(mask) - 1;
    uint32_t wbase = 0;
    if (lane == leader) wbase = atomicAdd(&cand_cnt[b], (uint32_t)__popcll(mask));
    wbase = __shfl(wbase, leader);
    if (pass) {
      uint32_t pos = wbase + (uint32_t)__popcll(mask & ((1ull << lane) - 1ull));
      if (pos < CCAP) {
        cand_key[b * CCAP + pos] = k;
        cand_idx[b * CCAP + pos] = (uint32_t)n;
      }
    }
  }
}

__global__ void k_rank(const uint32_t* __restrict__ cand_cnt, const uint32_t* __restrict__ cand_key,
                       const uint32_t* __restrict__ cand_idx, uint32_t* __restrict__ ordered) {
  int b = blockIdx.y;
  int g = blockIdx.x;
  uint32_t cnt = cand_cnt[b];
  if (cnt > CCAP) cnt = CCAP;
  int base = g * 256;
  if (base >= (int)cnt) return;  // uniform per block
  __shared__ uint64_t comp[CCAP];  // 32 KB
  for (int j = threadIdx.x; j < (int)cnt; j += 256) {
    comp[j] = ((uint64_t)cand_key[b * CCAP + j] << 32) | (uint32_t)(~cand_idx[b * CCAP + j]);
  }
  __syncthreads();
  int j0 = base + threadIdx.x;
  if (j0 < (int)cnt) {
    uint64_t mine = comp[j0];
    uint32_t r = 0;
    for (uint32_t j = 0; j < cnt; ++j) r += (comp[j] > mine) ? 1u : 0u;  // broadcast reads
    if (r < NCROSS) ordered[b * NCROSS + r] = ~(uint32_t)mine;  // recover idx
  }
}

__global__ void k_sort256(const uint32_t* __restrict__ ordered, uint32_t* __restrict__ sel,
                          float* __restrict__ out_si) {
  int b = blockIdx.x;
  int t = threadIdx.x;
  __shared__ uint32_t idxs[TOPK];
  uint32_t v = ordered[b * NCROSS + t];
  idxs[t] = v;
  __syncthreads();
  int r = 0;
  for (int j = 0; j < TOPK; ++j) r += (idxs[j] < v) ? 1 : 0;
  sel[b * TOPK + r] = v;
  out_si[b * TOPK + r] = (float)v;  // flat out buffer is read as f32
}

__global__ void k_gather(const float* __restrict__ features, const float* __restrict__ points,
                         const uint32_t* __restrict__ ordered, const uint32_t* __restrict__ sel,
                         float* __restrict__ out) {
  int g = blockIdx.x;
  int t = threadIdx.x;
  if (g < 1024) {  // cross_features: 8*1024 rows * 32 float4
    int flat = g * 256 + t;
    int row = flat >> 5;
    int c4 = flat & 31;
    int b = row >> 10, j = row & 1023;
    uint32_t idx = ordered[b * NCROSS + j];
    const float4* src = (const float4*)(features + ((size_t)b * NN + idx) * DD);
    ((float4*)(out + OFF_CROSS))[flat] = src[c4];
  } else if (g < 1280) {  // feat_sel: 8*256 rows * 32 float4
    int flat = (g - 1024) * 256 + t;
    int row = flat >> 5;
    int c4 = flat & 31;
    int b = row >> 8, j = row & 255;
    uint32_t idx = sel[b * TOPK + j];
    const float4* src = (const float4*)(features + ((size_t)b * NN + idx) * DD);
    ((float4*)(out + OFF_FEAT))[flat] = src[c4];
  } else {  // pts_sel: 8 blocks, 256 rows each, 3 floats
    int b = g - 1280;
    uint32_t idx = sel[b * TOPK + t];
    const float* src = points + ((size_t)b * NN + idx) * 3;
    float* dst = out + OFF_PTS + ((size_t)b * TOPK + t) * 3;
    dst[0] = src[0];
    dst[1] = src[1];
    dst[2] = src[2];
  }
}

extern "C" void kernel_launch(void* const* d_in, const int* in_sizes, int n_in,
                              void* d_out, int out_size, void* d_ws, size_t ws_size,
                              hipStream_t stream) {
  const float* cen  = (const float*)d_in[0];
  const float* cls  = (const float*)d_in[1];
  const float* pts  = (const float*)d_in[2];
  const float* feat = (const float*)d_in[3];
  float* out = (float*)d_out;

  uint32_t* ws = (uint32_t*)d_ws;
  uint32_t* hist     = ws;                      // BB*NBINS
  uint32_t* cand_cnt = hist + BB * NBINS;       // BB
  uint32_t* cutoff   = cand_cnt + BB;           // BB
  uint32_t* cand_key = cutoff + BB;             // BB*CCAP
  uint32_t* cand_idx = cand_key + BB * CCAP;    // BB*CCAP
  uint32_t* ordered  = cand_idx + BB * CCAP;    // BB*NCROSS
  uint32_t* sel      = ordered + BB * NCROSS;   // BB*TOPK
  uint32_t* keys     = sel + BB * TOPK;         // BB*NN

  int nz = BB * NBINS + BB;  // hist + cand_cnt (adjacent)
  k_init<<<(nz + 255) / 256, 256, 0, stream>>>(hist, nz);
  k_score<<<dim3(32, BB), 256, 0, stream>>>(cen, cls, keys, hist);
  k_select<<<BB, 256, 0, stream>>>(hist, cutoff);
  k_compact<<<dim3((NN + 255) / 256, BB), 256, 0, stream>>>(keys, cutoff, cand_cnt, cand_key, cand_idx);
  k_rank<<<dim3(CCAP / 256, BB), 256, 0, stream>>>(cand_cnt, cand_key, cand_idx, ordered);
  k_sort256<<<BB, 256, 0, stream>>>(ordered, sel, out + OFF_SI);
  k_gather<<<1288, 256, 0, stream>>>(feat, pts, ordered, sel, out);
}